// Round 5
// baseline (241.469 us; speedup 1.0000x reference)
//
#include <hip/hip_runtime.h>

typedef __attribute__((ext_vector_type(8))) short short8;
typedef __attribute__((ext_vector_type(4))) float f32x4;
union frag_u { short8 v; unsigned short u[8]; };

__device__ __forceinline__ float bf2f(unsigned short b) {
  unsigned int u = ((unsigned int)b) << 16;
  float f; __builtin_memcpy(&f, &u, 4); return f;
}
__device__ __forceinline__ unsigned short f2bf(float f) {
  unsigned int u; __builtin_memcpy(&u, &f, 4);
  return (unsigned short)((u + 0x7FFFu + ((u >> 16) & 1u)) >> 16);
}
__device__ __forceinline__ unsigned short hi_of(float f) { return f2bf(f); }
__device__ __forceinline__ unsigned short lo_of(float f) {
  unsigned short h = f2bf(f); return f2bf(f - bf2f(h));
}
__device__ __forceinline__ float sigm(float x) {
  return __builtin_amdgcn_rcpf(1.f + __expf(-x));
}
__device__ __forceinline__ float tanh_(float x) {
  return 1.f - 2.f * __builtin_amdgcn_rcpf(1.f + __expf(2.f * x));
}

// dtype detector: even-indexed uint16s of an f32 buffer are uniform mantissa
// halves (mostly insane bf16 exponents); of a bf16 buffer they are N(0,1)
// values (sane exponents 100..140). flag: 0 = bf16, 1 = f32.
__global__ void detect_dtype_kernel(const unsigned short* s, int* flag) {
  if (threadIdx.x == 0 && blockIdx.x == 0) {
    int insane = 0;
    for (int i = 0; i < 64; ++i) {
      unsigned short v = s[2 * i];
      int e = (v >> 7) & 0xFF;
      if (e < 100 || e > 140) insane++;
    }
    *flag = (insane >= 16) ? 1 : 0;
  }
}

// sA(16 x Kpad bf16, stride AS) @ W(K x N) -> sG[n][m]  (G stride 20)
// A-frag: lane holds A[m=lane&15][k=kc*32+quad*8+j]; B-frag: W[k][n=tile*16+(lane&15)]
// C/D: row m = quad*4+reg, col n = lane&15   [verified m89/m91]
// 16 waves: tiles strided by 16.
template <int AS, typename GetB, typename GetW>
__device__ __forceinline__ void mfma_layer(const unsigned short* sA, float* sG,
    int wave, int col, int quad, int kc_n, int ntiles, int N, GetB getb, GetW getw)
{
  for (int tile = wave; tile < ntiles; tile += 16) {
    int n = tile * 16 + col;
    float b = (n < N) ? getb(n) : 0.f;
    f32x4 acc = {b, b, b, b};
    for (int kc = 0; kc < kc_n; ++kc) {
      short8 a = *(const short8*)&sA[col * AS + kc * 32 + quad * 8];
      frag_u w;
      #pragma unroll
      for (int j = 0; j < 8; ++j) {
        int k = kc * 32 + quad * 8 + j;
        w.u[j] = (n < N) ? getw(k, n) : (unsigned short)0;
      }
      acc = __builtin_amdgcn_mfma_f32_16x16x32_bf16(a, w.v, acc, 0, 0, 0);
    }
    *(f32x4*)&sG[n * 20 + quad * 4] = acc;
  }
}

// relu(sG col) -> sA as bf16 hi at [0,N), optional lo at [loOff,loOff+N), zero pad to Kpad
template <int AS, bool LO>
__device__ __forceinline__ void relu_fill(const float* sG, unsigned short* sA,
                                          int tid, int N, int loOff, int Kpad) {
  for (int idx = tid; idx < 16 * Kpad; idx += 1024) {
    int m = idx & 15, n = idx >> 4;
    unsigned short v = 0;
    if (n < N) {
      v = f2bf(fmaxf(sG[n * 20 + m], 0.f));
    } else if (LO && n >= loOff && n < loOff + N) {
      float x = fmaxf(sG[(n - loOff) * 20 + m], 0.f);
      v = lo_of(x);
    }
    sA[m * AS + n] = v;
  }
}

// 1024 threads / 16 waves per block, 16 rows per block, grid = 512.
// Each of the 13 gate-tiles is owned by ONE wave; 800 activation items are
// 1/thread. KEY CHANGE vs prior round: the whole x slab (16 rows x 64 t x 7
// dims = exactly 1024 threads x 7 loads) is pre-staged into LDS (sX) before
// the recurrence, with f32->bf16 hi/lo conversion done ONCE. The LSTM loop
// then has ZERO global-memory ops, so __syncthreads no longer drains an
// in-flight global prefetch (vmcnt) every step — that drain was the fixed
// ~1000cy/interval cost that made occupancy increases useless.
template <bool F32>
__global__ __launch_bounds__(1024, 8) void value_net_kernel(
    const void* state_, const void* wih_, const void* whh_,
    const void* bih_, const void* bhh_,
    const void* w1_, const void* b1_, const void* w2_, const void* b2_,
    const void* w3_, const void* b3_, const void* w4_, const void* b4_,
    void* out_, const int* flag)
{
  if (flag && *flag != (F32 ? 1 : 0)) return;   // dtype mismatch -> other variant runs

  // A column layout, LSTM phase:
  //  bf16: [x(0..6) | h_hi(7..56) | h_lo(57..106) | 0-pad..127]           K=4x32
  //  f32 : [x_hi(0..6) | x_lo(7..13) | x_hi(14..20) | h_hi(21..70) |
  //         h_lo(71..120) | h_hi(121..170) | 0-pad..191]                  K=6x32
  //        paired with W rows [Wx_hi|Wx_hi|Wx_lo|Wh_hi|Wh_hi|Wh_lo] (tri-product)
  constexpr int AS = F32 ? 328 : 168;   // max Kpad (+8 pad): f32 L2 needs 320
  constexpr int KC = F32 ? 6 : 4;

  __shared__ __align__(16) unsigned short sA[16 * AS];
  __shared__ __align__(16) float sG[208 * 20];
  // x slab: [t][r][d] with d-stride padded to 8. F32 stores (hi,lo) ushort2.
  __shared__ __align__(16) unsigned char sXraw[F32 ? 64 * 16 * 8 * 4 : 64 * 16 * 8 * 2];

  const unsigned short* st16 = (const unsigned short*)state_;
  const float*          stf  = (const float*)state_;

  const int tid  = threadIdx.x;
  const int wave = tid >> 6;            // 0..15
  const int lane = tid & 63;
  const int col  = lane & 15;
  const int quad = lane >> 4;
  const int r0   = blockIdx.x * 16;

  // ---- zero sA (h0 = 0 and all K padding) ----
  {
    unsigned int* a32 = (unsigned int*)sA;
    constexpr int ZN = (16 * AS / 2 + 1023) / 1024;
    #pragma unroll
    for (int i = 0; i < ZN; ++i) {
      int idx = tid + i * 1024;
      if (idx < 16 * AS / 2) a32[idx] = 0;
    }
  }

  // ---- stage the full x slab: thread = (row, t), 7 dims each ----
  {
    int r = tid >> 6;      // 0..15
    int t = tid & 63;      // 0..63
    size_t g = (size_t)(r0 + r) * 832 + (size_t)t * 13 + 6;
    if constexpr (!F32) {
      unsigned short* sX = (unsigned short*)sXraw;
      #pragma unroll
      for (int d = 0; d < 7; ++d)
        sX[(t * 16 + r) * 8 + d] = st16[g + d];
    } else {
      ushort2* sX = (ushort2*)sXraw;
      #pragma unroll
      for (int d = 0; d < 7; ++d) {
        float f = stf[g + d];
        unsigned short h = f2bf(f);
        unsigned short l = f2bf(f - bf2f(h));
        ushort2 v; v.x = h; v.y = l;
        sX[(t * 16 + r) * 8 + d] = v;
      }
    }
  }

  // ---- LSTM weight getter ----
  auto W_lstm = [&](int k, int n) -> unsigned short {
    if constexpr (!F32) {
      const unsigned short* wih = (const unsigned short*)wih_;
      const unsigned short* whh = (const unsigned short*)whh_;
      if (k < 7)   return wih[k * 200 + n];
      if (k < 57)  return whh[(k - 7) * 200 + n];
      if (k < 107) return whh[(k - 57) * 200 + n];
      return (unsigned short)0;
    } else {
      const float* wih = (const float*)wih_;
      const float* whh = (const float*)whh_;
      if (k < 7)   return hi_of(wih[k * 200 + n]);
      if (k < 14)  return hi_of(wih[(k - 7) * 200 + n]);
      if (k < 21)  return lo_of(wih[(k - 14) * 200 + n]);
      if (k < 71)  return hi_of(whh[(k - 21) * 200 + n]);
      if (k < 121) return hi_of(whh[(k - 71) * 200 + n]);
      if (k < 171) return lo_of(whh[(k - 121) * 200 + n]);
      return (unsigned short)0;
    }
  };
  auto ldf = [&](const void* p, int i) -> float {
    if constexpr (F32) return ((const float*)p)[i];
    else               return bf2f(((const unsigned short*)p)[i]);
  };

  // ---- persistent LSTM weight fragments: 13 N-tiles over 16 waves ----
  const bool hasTile = (wave < 13);
  frag_u wf[KC];
  float  wb = 0.f;
  if (hasTile) {
    int n = wave * 16 + col;
    #pragma unroll
    for (int kc = 0; kc < KC; ++kc) {
      #pragma unroll
      for (int j = 0; j < 8; ++j) {
        int k = kc * 32 + quad * 8 + j;
        wf[kc].u[j] = (n < 200) ? W_lstm(k, n) : (unsigned short)0;
      }
    }
    wb = (n < 200) ? (ldf(bih_, n) + ldf(bhh_, n)) : 0.f;
  }

  // ---- activation work: item idx = u*16 + m, 800 over 1024 threads ----
  const bool iv = tid < 800;
  const int  im = tid & 15, iu = tid >> 4;
  float c_ = 0.f, hf = 0.f;

  // x-feed on item-free threads 800..911 (16 rows x 7 dims), LDS->LDS only
  const bool isx = (tid >= 800) && (tid < 912);
  const int  xm = (tid - 800) / 7, xd = (tid - 800) - ((tid - 800) / 7) * 7;
  auto xfeed = [&](int t) {
    if constexpr (!F32) {
      const unsigned short* sX = (const unsigned short*)sXraw;
      sA[xm * AS + xd] = sX[(t * 16 + xm) * 8 + xd];
    } else {
      const ushort2* sX = (const ushort2*)sXraw;
      ushort2 v = sX[(t * 16 + xm) * 8 + xd];
      sA[xm * AS + xd] = v.x;
      sA[xm * AS + 14 + xd] = v.x;
      sA[xm * AS + 7 + xd] = v.y;
    }
  };

  __syncthreads();
  if (isx) xfeed(0);     // x_0 (from sX; different threads wrote it -> after barrier)
  __syncthreads();

  // ---- LSTM: 64 steps, all-LDS (no vmcnt at any barrier) ----
  for (int t = 0; t < 64; ++t) {
    if (hasTile) {
      short8 a[KC];
      #pragma unroll
      for (int kc = 0; kc < KC; ++kc)
        a[kc] = *(const short8*)&sA[col * AS + kc * 32 + quad * 8];
      f32x4 acc = {wb, wb, wb, wb};
      #pragma unroll
      for (int kc = 0; kc < KC; ++kc)
        acc = __builtin_amdgcn_mfma_f32_16x16x32_bf16(a[kc], wf[kc].v, acc, 0, 0, 0);
      int n = wave * 16 + col;
      *(f32x4*)&sG[n * 20 + quad * 4] = acc;
    }
    __syncthreads();
    if (iv) {
      float gi = sG[iu * 20 + im];
      float gf = sG[(50 + iu) * 20 + im];
      float gg = sG[(100 + iu) * 20 + im];
      float go = sG[(150 + iu) * 20 + im];
      float cc = sigm(gf) * c_ + sigm(gi) * tanh_(gg);
      c_ = cc;
      float h = sigm(go) * tanh_(cc);
      if (t < 63) {
        unsigned short hb = f2bf(h);
        unsigned short hl = f2bf(h - bf2f(hb));
        if constexpr (!F32) { sA[im * AS + 7 + iu] = hb; sA[im * AS + 57 + iu] = hl; }
        else { sA[im * AS + 21 + iu] = hb; sA[im * AS + 121 + iu] = hb; sA[im * AS + 71 + iu] = hl; }
      } else hf = h;
    }
    if (isx && t < 63) xfeed(t + 1);
    __syncthreads();
  }

  // ---- tail MLP, fused ----
  // joint cols: bf16 [self(0..5)|h_hi(6..55)|h_lo(56..105)] K=106->128
  //             f32  [self_hi(0..5)|h_hi(6..55)|self_lo(56..61)|h_lo(62..111)] K=112->128
  {
    unsigned int* a32 = (unsigned int*)sA;
    constexpr int ZN = (16 * AS / 2 + 1023) / 1024;
    #pragma unroll
    for (int i = 0; i < ZN; ++i) {
      int idx = tid + i * 1024;
      if (idx < 16 * AS / 2) a32[idx] = 0;
    }
  }
  __syncthreads();
  if (iv) {
    unsigned short hb = f2bf(hf);
    unsigned short hl = f2bf(hf - bf2f(hb));
    sA[im * AS + 6 + iu] = hb;
    if constexpr (!F32) sA[im * AS + 56 + iu] = hl; else sA[im * AS + 62 + iu] = hl;
  }
  if (tid < 96) {
    int m = tid / 6, d = tid - (tid / 6) * 6;
    if constexpr (!F32) sA[m * AS + d] = st16[(size_t)(r0 + m) * 832 + d];
    else {
      float f = stf[(size_t)(r0 + m) * 832 + d];
      sA[m * AS + d] = hi_of(f); sA[m * AS + 56 + d] = lo_of(f);
    }
  }
  __syncthreads();

  // L1: -> 150
  mfma_layer<AS>(sA, sG, wave, col, quad, 4, 10, 150,
    [&](int n) { return ldf(b1_, n); },
    [&](int k, int n) -> unsigned short {
      if constexpr (!F32) {
        const unsigned short* w1 = (const unsigned short*)w1_;
        if (k < 56)  return w1[k * 150 + n];
        if (k < 106) return w1[(k - 50) * 150 + n];
        return (unsigned short)0;
      } else {
        const float* w1 = (const float*)w1_;
        if (k < 56)  return hi_of(w1[k * 150 + n]);
        if (k < 112) return hi_of(w1[(k - 56) * 150 + n]);
        return (unsigned short)0;
      }
    });
  __syncthreads();
  if constexpr (!F32) relu_fill<AS, false>(sG, sA, tid, 150, 160, 160);
  else                relu_fill<AS, true >(sG, sA, tid, 150, 150, 320);
  __syncthreads();

  // L2: 150 -> 100
  mfma_layer<AS>(sA, sG, wave, col, quad, F32 ? 10 : 5, 7, 100,
    [&](int n) { return ldf(b2_, n); },
    [&](int k, int n) -> unsigned short {
      if constexpr (!F32) {
        const unsigned short* w2 = (const unsigned short*)w2_;
        return (k < 150) ? w2[k * 100 + n] : (unsigned short)0;
      } else {
        const float* w2 = (const float*)w2_;
        if (k < 150) return hi_of(w2[k * 100 + n]);
        if (k < 300) return hi_of(w2[(k - 150) * 100 + n]);
        return (unsigned short)0;
      }
    });
  __syncthreads();
  if constexpr (!F32) relu_fill<AS, false>(sG, sA, tid, 100, 128, 128);
  else                relu_fill<AS, true >(sG, sA, tid, 100, 100, 224);
  __syncthreads();

  // L3: 100 -> 100
  mfma_layer<AS>(sA, sG, wave, col, quad, F32 ? 7 : 4, 7, 100,
    [&](int n) { return ldf(b3_, n); },
    [&](int k, int n) -> unsigned short {
      if constexpr (!F32) {
        const unsigned short* w3 = (const unsigned short*)w3_;
        return (k < 100) ? w3[k * 100 + n] : (unsigned short)0;
      } else {
        const float* w3 = (const float*)w3_;
        if (k < 100) return hi_of(w3[k * 100 + n]);
        if (k < 200) return hi_of(w3[(k - 100) * 100 + n]);
        return (unsigned short)0;
      }
    });
  __syncthreads();

  // L4: relu(sG) @ w4 + b4, f32 VALU, 16-lane shuffle reduce (first 256 threads)
  if (tid < 256) {
    int m = tid >> 4, j0 = tid & 15;
    float s = 0.f;
    for (int j = j0; j < 100; j += 16)
      s += fmaxf(sG[j * 20 + m], 0.f) * ldf(w4_, j);
    s += __shfl_xor(s, 8); s += __shfl_xor(s, 4);
    s += __shfl_xor(s, 2); s += __shfl_xor(s, 1);
    if (j0 == 0) {
      float v = s + ldf(b4_, 0);
      if constexpr (!F32) ((unsigned short*)out_)[r0 + m] = f2bf(v);
      else                ((float*)out_)[r0 + m] = v;
    }
  }
}

extern "C" void kernel_launch(void* const* d_in, const int* in_sizes, int n_in,
                              void* d_out, int out_size, void* d_ws, size_t ws_size,
                              hipStream_t stream) {
  (void)in_sizes; (void)n_in; (void)out_size;
  // d_in[1..10] (mlp1_* / attn_*) are dead code in the reference — unused.
  const void* state = d_in[0];
  const void* wih = d_in[11]; const void* whh = d_in[12];
  const void* bih = d_in[13]; const void* bhh = d_in[14];
  const void* w1  = d_in[15]; const void* b1  = d_in[16];
  const void* w2  = d_in[17]; const void* b2  = d_in[18];
  const void* w3  = d_in[19]; const void* b3  = d_in[20];
  const void* w4  = d_in[21]; const void* b4  = d_in[22];

  if (ws_size >= sizeof(int)) {
    int* flag = (int*)d_ws;
    detect_dtype_kernel<<<dim3(1), dim3(64), 0, stream>>>(
        (const unsigned short*)state, flag);
    value_net_kernel<false><<<dim3(512), dim3(1024), 0, stream>>>(
        state, wih, whh, bih, bhh, w1, b1, w2, b2, w3, b3, w4, b4, d_out, flag);
    value_net_kernel<true><<<dim3(512), dim3(1024), 0, stream>>>(
        state, wih, whh, bih, bhh, w1, b1, w2, b2, w3, b3, w4, b4, d_out, flag);
  } else {
    value_net_kernel<false><<<dim3(512), dim3(1024), 0, stream>>>(
        state, wih, whh, bih, bhh, w1, b1, w2, b2, w3, b3, w4, b4, d_out,
        (const int*)nullptr);
  }
}

// Round 6
// 230.210 us; speedup vs baseline: 1.0489x; 1.0489x over previous
//
#include <hip/hip_runtime.h>

typedef __attribute__((ext_vector_type(8))) short short8;
typedef __attribute__((ext_vector_type(4))) float f32x4;
union frag_u { short8 v; unsigned short u[8]; };

__device__ __forceinline__ float bf2f(unsigned short b) {
  unsigned int u = ((unsigned int)b) << 16;
  float f; __builtin_memcpy(&f, &u, 4); return f;
}
__device__ __forceinline__ unsigned short f2bf(float f) {
  unsigned int u; __builtin_memcpy(&u, &f, 4);
  return (unsigned short)((u + 0x7FFFu + ((u >> 16) & 1u)) >> 16);
}
__device__ __forceinline__ unsigned short hi_of(float f) { return f2bf(f); }
__device__ __forceinline__ unsigned short lo_of(float f) {
  unsigned short h = f2bf(f); return f2bf(f - bf2f(h));
}
__device__ __forceinline__ float sigm(float x) {
  return __builtin_amdgcn_rcpf(1.f + __expf(-x));
}
__device__ __forceinline__ float tanh_(float x) {
  return 1.f - 2.f * __builtin_amdgcn_rcpf(1.f + __expf(2.f * x));
}

// Fallback dtype detector (parallel): even-indexed uint16s of an f32 buffer
// are mantissa halves (insane bf16 exponents); of a bf16 buffer they are
// N(0,1) values (exponents 100..140). flag: 0 = bf16, 1 = f32.
__global__ void detect_dtype_kernel(const unsigned short* s, int* flag) {
  int i = threadIdx.x;   // 64 threads
  unsigned short v = s[2 * i];
  int e = (v >> 7) & 0xFF;
  unsigned long long m = __ballot(e < 100 || e > 140);
  if (i == 0) *flag = (__popcll(m) >= 16) ? 1 : 0;
}

// sA(16 x Kpad bf16, stride AS) @ W(K x N) -> sG[n][m]  (G stride 20)
// A-frag: lane holds A[m=lane&15][k=kc*32+quad*8+j]; B-frag: W[k][n=tile*16+(lane&15)]
// C/D: row m = quad*4+reg, col n = lane&15   [verified m89/m91]
// 16 waves: tiles strided by 16.
template <int AS, typename GetB, typename GetW>
__device__ __forceinline__ void mfma_layer(const unsigned short* sA, float* sG,
    int wave, int col, int quad, int kc_n, int ntiles, int N, GetB getb, GetW getw)
{
  for (int tile = wave; tile < ntiles; tile += 16) {
    int n = tile * 16 + col;
    float b = (n < N) ? getb(n) : 0.f;
    f32x4 acc = {b, b, b, b};
    for (int kc = 0; kc < kc_n; ++kc) {
      short8 a = *(const short8*)&sA[col * AS + kc * 32 + quad * 8];
      frag_u w;
      #pragma unroll
      for (int j = 0; j < 8; ++j) {
        int k = kc * 32 + quad * 8 + j;
        w.u[j] = (n < N) ? getw(k, n) : (unsigned short)0;
      }
      acc = __builtin_amdgcn_mfma_f32_16x16x32_bf16(a, w.v, acc, 0, 0, 0);
    }
    *(f32x4*)&sG[n * 20 + quad * 4] = acc;
  }
}

// relu(sG col) -> sA as bf16 hi at [0,N), optional lo at [loOff,loOff+N), zero pad to Kpad
template <int AS, bool LO>
__device__ __forceinline__ void relu_fill(const float* sG, unsigned short* sA,
                                          int tid, int N, int loOff, int Kpad) {
  for (int idx = tid; idx < 16 * Kpad; idx += 1024) {
    int m = idx & 15, n = idx >> 4;
    unsigned short v = 0;
    if (n < N) {
      v = f2bf(fmaxf(sG[n * 20 + m], 0.f));
    } else if (LO && n >= loOff && n < loOff + N) {
      float x = fmaxf(sG[(n - loOff) * 20 + m], 0.f);
      v = lo_of(x);
    }
    sA[m * AS + n] = v;
  }
}

// 1024 threads / 16 waves, 16 rows per block, grid = 512.
// SINGLE-PHASE LSTM: weight columns are gate-permuted (n_new = u*4+gate, so
// n_orig = (n_new&3)*50 + (n_new>>2)). Wave w's MFMA tile then holds all 4
// gates for its 4 u-values x 16 rows = 64 items = 64 lanes. The wave writes
// acc to its PRIVATE sG strip and reads back its own item's 4 gates
// (wave-local DS ordering — no barrier), runs the activation itself, and
// writes h into the double-buffered sA. -> ONE barrier per step (was 2),
// and MFMA/activation latency chains of different waves overlap freely.
// Waves 13..15 are dedicated x-feeders (register-prefetched global loads).
template <bool F32>
__global__ __launch_bounds__(1024, 8) void value_net_kernel(
    const void* state_, const void* wih_, const void* whh_,
    const void* bih_, const void* bhh_,
    const void* w1_, const void* b1_, const void* w2_, const void* b2_,
    const void* w3_, const void* b3_, const void* w4_, const void* b4_,
    void* out_, const int* flag)
{
  if (flag && *flag != (F32 ? 1 : 0)) return;   // fallback path: other variant runs

  // A column layout, LSTM phase:
  //  bf16: [x(0..6) | h_hi(7..56) | h_lo(57..106) | 0-pad..127]           K=4x32
  //  f32 : [x_hi(0..6) | x_lo(7..13) | x_hi(14..20) | h_hi(21..70) |
  //         h_lo(71..120) | h_hi(121..170) | 0-pad..191]                  K=6x32
  //        paired with W rows [Wx_hi|Wx_hi|Wx_lo|Wh_hi|Wh_hi|Wh_lo] (tri-product)
  constexpr int AS = F32 ? 328 : 168;   // max Kpad (+8 pad): f32 L2 needs 320
  constexpr int KC = F32 ? 6 : 4;

  __shared__ __align__(16) unsigned short sA[2][16 * AS];  // double-buffered
  __shared__ __align__(16) float sG[208 * 20];

  const unsigned short* st16 = (const unsigned short*)state_;
  const float*          stf  = (const float*)state_;

  const int tid  = threadIdx.x;
  const int wave = tid >> 6;            // 0..15
  const int lane = tid & 63;
  const int col  = lane & 15;
  const int quad = lane >> 4;
  const int r0   = blockIdx.x * 16;

  // ---- zero BOTH sA buffers (h0 = 0 and all K padding) ----
  {
    unsigned int* a32 = (unsigned int*)&sA[0][0];
    constexpr int ZT = 16 * AS;        // uints across both buffers
    #pragma unroll
    for (int i = 0; i < (ZT + 1023) / 1024; ++i) {
      int idx = tid + i * 1024;
      if (idx < ZT) a32[idx] = 0;
    }
  }

  // ---- LSTM weight getter (n is ORIGINAL column index) ----
  auto W_lstm = [&](int k, int n) -> unsigned short {
    if constexpr (!F32) {
      const unsigned short* wih = (const unsigned short*)wih_;
      const unsigned short* whh = (const unsigned short*)whh_;
      if (k < 7)   return wih[k * 200 + n];
      if (k < 57)  return whh[(k - 7) * 200 + n];
      if (k < 107) return whh[(k - 57) * 200 + n];
      return (unsigned short)0;
    } else {
      const float* wih = (const float*)wih_;
      const float* whh = (const float*)whh_;
      if (k < 7)   return hi_of(wih[k * 200 + n]);
      if (k < 14)  return hi_of(wih[(k - 7) * 200 + n]);
      if (k < 21)  return lo_of(wih[(k - 14) * 200 + n]);
      if (k < 71)  return hi_of(whh[(k - 21) * 200 + n]);
      if (k < 121) return hi_of(whh[(k - 71) * 200 + n]);
      if (k < 171) return lo_of(whh[(k - 121) * 200 + n]);
      return (unsigned short)0;
    }
  };
  auto ldf = [&](const void* p, int i) -> float {
    if constexpr (F32) return ((const float*)p)[i];
    else               return bf2f(((const unsigned short*)p)[i]);
  };

  // ---- persistent LSTM weight fragments: 13 gate-permuted N-tiles ----
  const bool hasTile = (wave < 13);
  frag_u wf[KC];
  float  wb = 0.f;
  if (hasTile) {
    int nn = wave * 16 + col;                              // permuted col
    int no = (nn < 200) ? ((nn & 3) * 50 + (nn >> 2)) : 0; // original col
    #pragma unroll
    for (int kc = 0; kc < KC; ++kc) {
      #pragma unroll
      for (int j = 0; j < 8; ++j) {
        int k = kc * 32 + quad * 8 + j;
        wf[kc].u[j] = (nn < 200) ? W_lstm(k, no) : (unsigned short)0;
      }
    }
    wb = (nn < 200) ? (ldf(bih_, no) + ldf(bhh_, no)) : 0.f;
  }

  // per-lane LSTM item: (m = col, u = wave*4 + quad)
  const int  u_   = wave * 4 + quad;
  const bool iact = hasTile && (u_ < 50);
  float c_ = 0.f, hf = 0.f;

  // ---- x-feed: waves 13..15, threads 832..943 (16 rows x 7 dims) ----
  const bool isx = (tid >= 832) && (tid < 944);
  const int  xm = (tid - 832) / 7, xd = (tid - 832) - ((tid - 832) / 7) * 7;
  auto xgidx = [&](int t) -> size_t { return (size_t)(r0 + xm) * 832 + t * 13 + 6 + xd; };
  auto xwrite = [&](unsigned short* sAw, float fv, unsigned short bv) {
    if constexpr (!F32) { sAw[xm * AS + xd] = bv; }
    else {
      unsigned short h = f2bf(fv);
      sAw[xm * AS + xd] = h; sAw[xm * AS + 14 + xd] = h;
      sAw[xm * AS + 7 + xd] = f2bf(fv - bf2f(h));
    }
  };
  unsigned short xv16 = 0; float xvf = 0.f;   // prefetched x_{t+1}

  __syncthreads();
  if (isx) {   // x_0 into buf0 + prefetch x_1
    if constexpr (!F32) { xwrite(&sA[0][0], 0.f, st16[xgidx(0)]); xv16 = st16[xgidx(1)]; }
    else                { xwrite(&sA[0][0], stf[xgidx(0)], 0);    xvf  = stf[xgidx(1)]; }
  }
  __syncthreads();

  // ---- LSTM: 64 steps, ONE barrier per step ----
  for (int t = 0; t < 64; ++t) {
    const unsigned short* sAr = &sA[t & 1][0];
    unsigned short*       sAw = &sA[(t & 1) ^ 1][0];

    if (hasTile) {
      short8 a[KC];
      #pragma unroll
      for (int kc = 0; kc < KC; ++kc)
        a[kc] = *(const short8*)&sAr[col * AS + kc * 32 + quad * 8];
      f32x4 acc = {wb, wb, wb, wb};
      #pragma unroll
      for (int kc = 0; kc < KC; ++kc)
        acc = __builtin_amdgcn_mfma_f32_16x16x32_bf16(a[kc], wf[kc].v, acc, 0, 0, 0);
      // park tile in this wave's private sG strip (n_new = wave*16+col)
      *(f32x4*)&sG[(wave * 16 + col) * 20 + quad * 4] = acc;

      if (iact) {
        // wave-local readback: item (m=col, u=u_) gates at n_new = u_*4+g
        int nb = (wave * 16 + quad * 4);
        float gi = sG[(nb + 0) * 20 + col];
        float gf = sG[(nb + 1) * 20 + col];
        float gg = sG[(nb + 2) * 20 + col];
        float go = sG[(nb + 3) * 20 + col];
        float cc = sigm(gf) * c_ + sigm(gi) * tanh_(gg);
        c_ = cc;
        float h = sigm(go) * tanh_(cc);
        if (t < 63) {
          unsigned short hb = f2bf(h);
          unsigned short hl = f2bf(h - bf2f(hb));
          if constexpr (!F32) {
            sAw[col * AS + 7 + u_] = hb; sAw[col * AS + 57 + u_] = hl;
          } else {
            sAw[col * AS + 21 + u_] = hb; sAw[col * AS + 121 + u_] = hb;
            sAw[col * AS + 71 + u_] = hl;
          }
        } else hf = h;
      }
    } else if (isx && t < 63) {
      if constexpr (!F32) xwrite(sAw, 0.f, xv16); else xwrite(sAw, xvf, 0);
      if (t < 62) { if constexpr (!F32) xv16 = st16[xgidx(t + 2)]; else xvf = stf[xgidx(t + 2)]; }
    }
    __syncthreads();
  }

  // ---- tail MLP, fused (uses sA[0]) ----
  // joint cols: bf16 [self(0..5)|h_hi(6..55)|h_lo(56..105)] K=106->128
  //             f32  [self_hi(0..5)|h_hi(6..55)|self_lo(56..61)|h_lo(62..111)] K=112->128
  unsigned short* sA0 = &sA[0][0];
  {
    unsigned int* a32 = (unsigned int*)sA0;
    #pragma unroll
    for (int i = 0; i < (16 * AS / 2 + 1023) / 1024; ++i) {
      int idx = tid + i * 1024;
      if (idx < 16 * AS / 2) a32[idx] = 0;
    }
  }
  __syncthreads();
  if (iact) {
    unsigned short hb = f2bf(hf);
    unsigned short hl = f2bf(hf - bf2f(hb));
    sA0[col * AS + 6 + u_] = hb;
    if constexpr (!F32) sA0[col * AS + 56 + u_] = hl; else sA0[col * AS + 62 + u_] = hl;
  }
  if (tid < 96) {
    int m = tid / 6, d = tid - (tid / 6) * 6;
    if constexpr (!F32) sA0[m * AS + d] = st16[(size_t)(r0 + m) * 832 + d];
    else {
      float f = stf[(size_t)(r0 + m) * 832 + d];
      sA0[m * AS + d] = hi_of(f); sA0[m * AS + 56 + d] = lo_of(f);
    }
  }
  __syncthreads();

  // L1: -> 150
  mfma_layer<AS>(sA0, sG, wave, col, quad, 4, 10, 150,
    [&](int n) { return ldf(b1_, n); },
    [&](int k, int n) -> unsigned short {
      if constexpr (!F32) {
        const unsigned short* w1 = (const unsigned short*)w1_;
        if (k < 56)  return w1[k * 150 + n];
        if (k < 106) return w1[(k - 50) * 150 + n];
        return (unsigned short)0;
      } else {
        const float* w1 = (const float*)w1_;
        if (k < 56)  return hi_of(w1[k * 150 + n]);
        if (k < 112) return hi_of(w1[(k - 56) * 150 + n]);
        return (unsigned short)0;
      }
    });
  __syncthreads();
  if constexpr (!F32) relu_fill<AS, false>(sG, sA0, tid, 150, 160, 160);
  else                relu_fill<AS, true >(sG, sA0, tid, 150, 150, 320);
  __syncthreads();

  // L2: 150 -> 100
  mfma_layer<AS>(sA0, sG, wave, col, quad, F32 ? 10 : 5, 7, 100,
    [&](int n) { return ldf(b2_, n); },
    [&](int k, int n) -> unsigned short {
      if constexpr (!F32) {
        const unsigned short* w2 = (const unsigned short*)w2_;
        return (k < 150) ? w2[k * 100 + n] : (unsigned short)0;
      } else {
        const float* w2 = (const float*)w2_;
        if (k < 150) return hi_of(w2[k * 100 + n]);
        if (k < 300) return hi_of(w2[(k - 150) * 100 + n]);
        return (unsigned short)0;
      }
    });
  __syncthreads();
  if constexpr (!F32) relu_fill<AS, false>(sG, sA0, tid, 100, 128, 128);
  else                relu_fill<AS, true >(sG, sA0, tid, 100, 100, 224);
  __syncthreads();

  // L3: 100 -> 100
  mfma_layer<AS>(sA0, sG, wave, col, quad, F32 ? 7 : 4, 7, 100,
    [&](int n) { return ldf(b3_, n); },
    [&](int k, int n) -> unsigned short {
      if constexpr (!F32) {
        const unsigned short* w3 = (const unsigned short*)w3_;
        return (k < 100) ? w3[k * 100 + n] : (unsigned short)0;
      } else {
        const float* w3 = (const float*)w3_;
        if (k < 100) return hi_of(w3[k * 100 + n]);
        if (k < 200) return hi_of(w3[(k - 100) * 100 + n]);
        return (unsigned short)0;
      }
    });
  __syncthreads();

  // L4: relu(sG) @ w4 + b4, f32 VALU, 16-lane shuffle reduce (first 256 threads)
  if (tid < 256) {
    int m = tid >> 4, j0 = tid & 15;
    float s = 0.f;
    for (int j = j0; j < 100; j += 16)
      s += fmaxf(sG[j * 20 + m], 0.f) * ldf(w4_, j);
    s += __shfl_xor(s, 8); s += __shfl_xor(s, 4);
    s += __shfl_xor(s, 2); s += __shfl_xor(s, 1);
    if (j0 == 0) {
      float v = s + ldf(b4_, 0);
      if constexpr (!F32) ((unsigned short*)out_)[r0 + m] = f2bf(v);
      else                ((float*)out_)[r0 + m] = v;
    }
  }
}

extern "C" void kernel_launch(void* const* d_in, const int* in_sizes, int n_in,
                              void* d_out, int out_size, void* d_ws, size_t ws_size,
                              hipStream_t stream) {
  (void)n_in; (void)out_size;
  // d_in[1..10] (mlp1_* / attn_*) are dead code in the reference — unused.
  const void* state = d_in[0];
  const void* wih = d_in[11]; const void* whh = d_in[12];
  const void* bih = d_in[13]; const void* bhh = d_in[14];
  const void* w1  = d_in[15]; const void* b1  = d_in[16];
  const void* w2  = d_in[17]; const void* b2  = d_in[18];
  const void* w3  = d_in[19]; const void* b3  = d_in[20];
  const void* w4  = d_in[21]; const void* b4  = d_in[22];

  // Host-side dtype selection from the state buffer byte size: one launch,
  // no detect kernel, no dead-variant dispatch.
  const long long F32B  = 8192LL * 64 * 13 * 4;
  const long long BF16B = 8192LL * 64 * 13 * 2;
  long long sz = in_sizes ? (long long)in_sizes[0] : -1;

  if (sz == F32B) {
    value_net_kernel<true><<<dim3(512), dim3(1024), 0, stream>>>(
        state, wih, whh, bih, bhh, w1, b1, w2, b2, w3, b3, w4, b4, d_out,
        (const int*)nullptr);
  } else if (sz == BF16B) {
    value_net_kernel<false><<<dim3(512), dim3(1024), 0, stream>>>(
        state, wih, whh, bih, bhh, w1, b1, w2, b2, w3, b3, w4, b4, d_out,
        (const int*)nullptr);
  } else if (ws_size >= sizeof(int)) {
    // Fallback: on-device detect + both variants (one exits immediately).
    int* flag = (int*)d_ws;
    detect_dtype_kernel<<<dim3(1), dim3(64), 0, stream>>>(
        (const unsigned short*)state, flag);
    value_net_kernel<false><<<dim3(512), dim3(1024), 0, stream>>>(
        state, wih, whh, bih, bhh, w1, b1, w2, b2, w3, b3, w4, b4, d_out, flag);
    value_net_kernel<true><<<dim3(512), dim3(1024), 0, stream>>>(
        state, wih, whh, bih, bhh, w1, b1, w2, b2, w3, b3, w4, b4, d_out, flag);
  } else {
    value_net_kernel<false><<<dim3(512), dim3(1024), 0, stream>>>(
        state, wih, whh, bih, bhh, w1, b1, w2, b2, w3, b3, w4, b4, d_out,
        (const int*)nullptr);
  }
}